// Round 1
// baseline (22185.519 us; speedup 1.0000x reference)
//
#include <hip/hip_runtime.h>
#include <stdint.h>

// Problem: D-FPS. points_xyz (16, 131072, 3) fp32 -> indices (16, 4096) int32.
//
// Round 15 = round 14 (8832 us) restructured for latency-hiding co-residency:
// NBLK 16->32 (CHUNK 8192->4096, LDS 96.5->48.2 KB) so TWO blocks fit per CU
// (2048 threads = 32 waves = 100% occupancy), and the grid mapping pairs each
// CU with blocks from two DIFFERENT batches (batch x and x+8, both resident
// on XCD x so the slot protocol stays XCD-L2-local). Rationale: per-iter time
// 5177 cy vs ~2500-3500 cy of modeled work -> ~40-50% CU idle while one wave
// polls the cross-block slots and 15 waves park at barrier2. Independent
// batches tick independently; B's distance phase fills A's poll/barrier idle
// and vice versa. Worst case (phases lock) per-CU pipe work is unchanged and
// the two latency chains still overlap -> neutral; best case hides most of
// one batch's compute inside the other's chain.
// Protocol byte-identical to r8/r13/r14, just 32-wide: one tagged slot word
// per block per parity, ONE relaxed polling wave, 5-step butterfly (lanes
// 0..31 closed hypercube) + lane-0 broadcast.
//
// Locked-in lessons (r2-r14):
//  - relaxed-only AGENT atomics; tag+payload in one 64-bit word (r7/r8:
//    agent acquire/release = chip-wide cache-maintenance storms).
//  - ONE relaxed polling wave per block (r5/r10).
//  - hardware barrier beats software tag-spin for intra-block ordering (r13).
//  - points in LDS SoA; allocator never keeps them register-resident (r3-r5).
//  - FMA-chain distance d = fma(dz,dz, fma(dy,dy, dx*dx)), subs exact-rounded
//    (r2: bit-exact vs reference trajectory).
//  - removals help; rearrangements and added traffic regress (r9-r12).

#define BATCH 16
#define NPTS  131072
#define NSAMP 4096
#define NBLK  32                  // blocks per batch (r15: was 16)
#define TPB   1024                // 16 waves
#define CHUNK (NPTS / NBLK)       // 4096 points per block
#define PPT   (CHUNK / TPB)       // 4 points per thread
#define NWAVE (TPB / 64)

typedef unsigned long long u64;
typedef unsigned int u32;

// Global slot word (8B, one per block per parity):
//   [63:32] dist bits (>=0 -> monotone) | [31:15] idx (17b) | [14:0] iter tag
// Poison 0xAA.. -> tag 0x2AAA; zero-init -> tag 0; live tags are 1..4095.
// Ring-2 by parity; ordering via the value-dependence chain (r8-proven).

__global__ void fps_init_kernel(u64* __restrict__ ws) {
    int i = blockIdx.x * blockDim.x + threadIdx.x;
    if (i < BATCH * 2 * NBLK) ws[i] = 0ull;
}

__global__ __launch_bounds__(TPB, 8) void fps_kernel(
        const float* __restrict__ xyz, int* __restrict__ out,
        u64* __restrict__ gslot) {
    // ---- grid mapping: XCD = blockIdx % 8 (round-robin dispatch). ----
    // slot s = blockIdx/8 indexes dispatch order within the XCD; s and s+32
    // land on the same CU (second fill pass over the XCD's 32 CUs). Pair
    // batches x (s<32) and x+8 (s>=32): every CU hosts two blocks from two
    // DIFFERENT batches; each batch's 32 blocks stay on one XCD (L2-local
    // slot traffic, as in r8-r14 where blk%8 == b%8).
    const int g     = blockIdx.x;
    const int x     = g & 7;               // XCD
    const int s     = g >> 3;              // 0..63 slot within XCD
    const int b     = x + ((s >> 5) << 3); // batch: x or x+8
    const int chunk = s & 31;              // 0..31
    const int tid   = threadIdx.x;
    const int w     = tid >> 6;
    const int lane  = tid & 63;

    const float* bxyz = xyz + (size_t)b * NPTS * 3;
    const int base = chunk * CHUNK;

    // ---- LDS: SoA points + plain red keys + plain bc (all barrier-ordered) --
    __shared__ float2 sxy[CHUNK];          // 32 KB
    __shared__ float  szz[CHUNK];          // 16 KB
    __shared__ u64 red[NWAVE];
    __shared__ u32 bc;                     // winning index, barrier-ordered
    for (int i = tid; i < CHUNK; i += TPB) {
        size_t p = (size_t)(base + i) * 3;
        sxy[i] = make_float2(bxyz[p + 0], bxyz[p + 1]);
        szz[i] = bxyz[p + 2];
    }
    if (tid == 0 && chunk == 0) out[b * NSAMP] = 0; // iter 0 emits index 0
    __syncthreads();   // staging visibility

    float pd[PPT];
#pragma unroll
    for (int k = 0; k < PPT; ++k) pd[k] = __builtin_inff();

    float cx = bxyz[0], cy = bxyz[1], cz = bxyz[2];

    u64* gs = gslot + (size_t)b * 2 * NBLK;   // [2][NBLK]

    for (int it = 1; it < NSAMP; ++it) {
        const int par = it & 1;
        u64* gsp = gs + par * NBLK;

        // ---- update min-dists + local argmax (LDS + registers) ----
        // Verified arithmetic (round 2, absmax 0): FMA-contracted
        //   d = fma(dz,dz, fma(dy,dy, dx*dx)), subs exact-rounded.
        float bd = -1.0f;
        int   bk = 0;
#pragma unroll
        for (int k = 0; k < PPT; ++k) {
            int i = tid + TPB * k;
            float2 xy = sxy[i];
            float  z  = szz[i];
            float dx = __fsub_rn(xy.x, cx);
            float dy = __fsub_rn(xy.y, cy);
            float dz = __fsub_rn(z,    cz);
            float d  = __builtin_fmaf(dz, dz,
                         __builtin_fmaf(dy, dy, __fmul_rn(dx, dx)));
            float nd = fminf(pd[k], d);
            pd[k] = nd;
            // strict >: earliest k wins (gi ascends with k) = first-occurrence
            if (nd > bd) { bd = nd; bk = k; }
        }
        u32 gi = (u32)(base + tid + TPB * bk);
        u64 key = ((u64)__float_as_uint(bd) << 32) | (u64)(~gi);

        // ---- wave butterfly (max dist, then min index) ----
#pragma unroll
        for (int off = 1; off <= 32; off <<= 1) {
            u64 o = __shfl_xor(key, off, 64);
            key = key > o ? key : o;
        }
        if (lane == 0) red[w] = key;      // plain store; barrier1 orders it
        __syncthreads();                   // barrier1 (replaced red tag-poll, r13)

        if (w == 0) {
            // ---- combine 16 plain keys (real keys > 0; lanes 16+ feed 0) ----
            u64 k2 = (lane < NWAVE) ? red[lane] : 0ull;
#pragma unroll
            for (int off = 1; off <= 8; off <<= 1) {
                u64 o = __shfl_xor(k2, off, 64);
                k2 = k2 > o ? k2 : o;
            }
            // ---- ONE relaxed agent store publishes the block winner ----
            if (lane == 0) {
                u32 db  = (u32)(k2 >> 32);
                u32 idx = ~(u32)k2;        // = gi (fits 17 bits)
                __hip_atomic_store(&gsp[chunk],
                                   ((u64)db << 32) | ((u64)idx << 15) | (u64)it,
                                   __ATOMIC_RELAXED, __HIP_MEMORY_SCOPE_AGENT);
            }
            // ---- relaxed poll of the 32 slot words (r8 protocol, wider) ----
            u64 v; bool ok;
            do {
                v  = (lane < NBLK)
                       ? __hip_atomic_load(&gsp[lane], __ATOMIC_RELAXED,
                                           __HIP_MEMORY_SCOPE_AGENT)
                       : 0ull;
                ok = (lane < NBLK) ? ((v & 0x7FFFull) == (u64)it) : true;
            } while (__ballot(ok) != ~0ull);
            u64 k3 = 0ull;
            if (lane < NBLK) {
                u32 db  = (u32)(v >> 32);
                u32 idx = (u32)((v >> 15) & 0x1FFFFu);
                k3 = ((u64)db << 32) | (u64)(~idx);
            }
            // 5-step butterfly: lanes 0..31 are a closed hypercube; then
            // broadcast lane0's winner to the whole wave.
#pragma unroll
            for (int off = 1; off <= 16; off <<= 1) {
                u64 o = __shfl_xor(k3, off, 64);
                k3 = k3 > o ? k3 : o;
            }
            k3 = __shfl(k3, 0, 64);
            u32 widx = ~(u32)k3;
            if (lane == 0) {
                if (chunk == 0) out[b * NSAMP + it] = (int)widx;
                bc = widx;                 // plain store; barrier2 orders it
            }
        }
        __syncthreads();                   // barrier2 (replaces the bc tag-spin)

        u32 widx = bc;                     // barrier-ordered plain read
        cx = bxyz[3 * (size_t)widx + 0];   // same-address broadcast load
        cy = bxyz[3 * (size_t)widx + 1];
        cz = bxyz[3 * (size_t)widx + 2];
    }
}

extern "C" void kernel_launch(void* const* d_in, const int* in_sizes, int n_in,
                              void* d_out, int out_size, void* d_ws, size_t ws_size,
                              hipStream_t stream) {
    const float* xyz = (const float*)d_in[0];
    int* out = (int*)d_out;
    u64* gslot = (u64*)d_ws;   // [BATCH][2][NBLK] u64 = 8 KB

    hipLaunchKernelGGL(fps_init_kernel, dim3(1), dim3(1024), 0, stream, gslot);
    hipLaunchKernelGGL(fps_kernel, dim3(BATCH * NBLK), dim3(TPB), 0, stream,
                       xyz, out, gslot);
}

// Round 2
// 7062.238 us; speedup vs baseline: 3.1414x; 3.1414x over previous
//
#include <hip/hip_runtime.h>
#include <stdint.h>

// Problem: D-FPS. points_xyz (16, 131072, 3) fp32 -> indices (16, 4096) int32.
//
// Round 16 = round 14 structure (best: 8832 us; NBLK=16, one block per CU)
// with every shuffle-butterfly replaced by DPP reductions.
// r15 post-mortem (22186 us, REVERTED): widening the sync fan-in to 32 blocks
// + 2 blocks/CU made the fabric poll superlinearly slower (FETCH 19.5->94 MB)
// and added contention skew. Lesson: fan-in width is the enemy; occupancy is
// worthless here. The per-iter critical path is latency, and ~1-1.5k cy of it
// was __shfl butterflies: u64 __shfl_xor = 2x ds_bpermute (LDS-pipe round
// trip ~100 cy) per step, in dependent chains of 6+4+4 steps. DPP row ops
// (v_mov_dpp row_shr / row_bcast) are VALU-pipe (~3 cy), same associative
// max -> bit-identical result, no LDS traffic.
// Cross-block protocol byte-identical to r8/r13/r14 (relaxed, tagged, ring-2).
//
// Locked-in lessons (r2-r15):
//  - relaxed-only AGENT atomics; tag+payload in one 64-bit word (r7/r8:
//    agent acquire/release = chip-wide cache-maintenance storms).
//  - ONE relaxed polling wave per block (r5/r10); NARROW fan-in (r15).
//  - hardware barrier beats software tag-spin for intra-block ordering (r13).
//  - one block per CU; co-residency of independent batches regresses (r15).
//  - points in LDS SoA; allocator never keeps them register-resident (r3-r5).
//  - FMA-chain distance d = fma(dz,dz, fma(dy,dy, dx*dx)), subs exact-rounded
//    (r2: bit-exact vs reference trajectory).
//  - removals help; rearrangements and added traffic regress (r9-r12).

#define BATCH 16
#define NPTS  131072
#define NSAMP 4096
#define NBLK  16                  // blocks per batch
#define TPB   1024                // 16 waves
#define CHUNK (NPTS / NBLK)       // 8192 points per block
#define PPT   (CHUNK / TPB)       // 8 points per thread
#define NWAVE (TPB / 64)

typedef unsigned long long u64;
typedef unsigned int u32;

// ---- DPP 64-bit lexicographic max-reduce helpers --------------------------
// key = dist_bits(32) | ~gi(32): u64 max == (max dist, then min index).
// update_dpp(old=0,...): lanes with no valid source read 0; all real keys
// are > 0 (low half ~gi >= 0xFFFE0000), so 0 is the identity.
#define DPP_ROW_SHR(n)  (0x110 | (n))
#define DPP_BCAST15     0x142
#define DPP_BCAST31     0x143

template <int CTRL>
__device__ __forceinline__ u64 dpp_max_step(u64 key) {
    u32 lo = (u32)key, hi = (u32)(key >> 32);
    u32 olo = (u32)__builtin_amdgcn_update_dpp(0, (int)lo, CTRL, 0xF, 0xF, false);
    u32 ohi = (u32)__builtin_amdgcn_update_dpp(0, (int)hi, CTRL, 0xF, 0xF, false);
    u64 o = ((u64)ohi << 32) | (u64)olo;
    return o > key ? o : key;
}

// Full-wave (64 lane) max; result valid in lane 63.
__device__ __forceinline__ u64 dpp_max64(u64 key) {
    key = dpp_max_step<DPP_ROW_SHR(1)>(key);
    key = dpp_max_step<DPP_ROW_SHR(2)>(key);
    key = dpp_max_step<DPP_ROW_SHR(4)>(key);
    key = dpp_max_step<DPP_ROW_SHR(8)>(key);
    key = dpp_max_step<DPP_BCAST15>(key);
    key = dpp_max_step<DPP_BCAST31>(key);
    return key;
}

// Row (16 lane) max over lanes 0..15 (others must hold 0); valid in lane 15.
__device__ __forceinline__ u64 dpp_max16(u64 key) {
    key = dpp_max_step<DPP_ROW_SHR(1)>(key);
    key = dpp_max_step<DPP_ROW_SHR(2)>(key);
    key = dpp_max_step<DPP_ROW_SHR(4)>(key);
    key = dpp_max_step<DPP_ROW_SHR(8)>(key);
    return key;
}

// Global slot word (8B, one per block per parity):
//   [63:32] dist bits (>=0 -> monotone) | [31:15] idx (17b) | [14:0] iter tag
// Poison 0xAA.. -> tag 0x2AAA; zero-init -> tag 0; live tags are 1..4095.
// Ring-2 by parity; ordering via the value-dependence chain (r8-proven).

__global__ void fps_init_kernel(u64* __restrict__ ws) {
    int i = blockIdx.x * blockDim.x + threadIdx.x;
    if (i < BATCH * 2 * NBLK) ws[i] = 0ull;
}

__global__ __launch_bounds__(TPB, 4) void fps_kernel(
        const float* __restrict__ xyz, int* __restrict__ out,
        u64* __restrict__ gslot) {
    const int blk   = blockIdx.x;
    const int b     = blk & 15;    // batch: a batch's 16 blocks share blk%8
    const int chunk = blk >> 4;    //        -> same XCD (round-robin dispatch)
    const int tid   = threadIdx.x;
    const int w     = tid >> 6;
    const int lane  = tid & 63;

    const float* bxyz = xyz + (size_t)b * NPTS * 3;
    const int base = chunk * CHUNK;

    // ---- LDS: SoA points + plain red keys + plain bc (all barrier-ordered) --
    __shared__ float2 sxy[CHUNK];          // 64 KB
    __shared__ float  szz[CHUNK];          // 32 KB
    __shared__ u64 red[NWAVE];
    __shared__ u32 bc;                     // winning index, barrier-ordered
    for (int i = tid; i < CHUNK; i += TPB) {
        size_t p = (size_t)(base + i) * 3;
        sxy[i] = make_float2(bxyz[p + 0], bxyz[p + 1]);
        szz[i] = bxyz[p + 2];
    }
    if (tid == 0 && chunk == 0) out[b * NSAMP] = 0; // iter 0 emits index 0
    __syncthreads();   // staging visibility

    float pd[PPT];
#pragma unroll
    for (int k = 0; k < PPT; ++k) pd[k] = __builtin_inff();

    float cx = bxyz[0], cy = bxyz[1], cz = bxyz[2];

    u64* gs = gslot + (size_t)b * 2 * NBLK;   // [2][NBLK]

    for (int it = 1; it < NSAMP; ++it) {
        const int par = it & 1;
        u64* gsp = gs + par * NBLK;

        // ---- update min-dists + local argmax (LDS + registers) ----
        // Verified arithmetic (round 2, absmax 0): FMA-contracted
        //   d = fma(dz,dz, fma(dy,dy, dx*dx)), subs exact-rounded.
        float bd = -1.0f;
        int   bk = 0;
#pragma unroll
        for (int k = 0; k < PPT; ++k) {
            int i = tid + TPB * k;
            float2 xy = sxy[i];
            float  z  = szz[i];
            float dx = __fsub_rn(xy.x, cx);
            float dy = __fsub_rn(xy.y, cy);
            float dz = __fsub_rn(z,    cz);
            float d  = __builtin_fmaf(dz, dz,
                         __builtin_fmaf(dy, dy, __fmul_rn(dx, dx)));
            float nd = fminf(pd[k], d);
            pd[k] = nd;
            // strict >: earliest k wins (gi ascends with k) = first-occurrence
            if (nd > bd) { bd = nd; bk = k; }
        }
        u32 gi = (u32)(base + tid + TPB * bk);
        u64 key = ((u64)__float_as_uint(bd) << 32) | (u64)(~gi);

        // ---- wave max via DPP (VALU pipe; was 6x u64 __shfl_xor chain) ----
        key = dpp_max64(key);              // valid in lane 63
        if (lane == 63) red[w] = key;      // plain store; barrier1 orders it
        __syncthreads();                   // barrier1 (replaced red tag-poll, r13)

        if (w == 0) {
            // ---- combine 16 plain keys (real keys > 0; lanes 16+ feed 0) ----
            u64 k2 = (lane < NWAVE) ? red[lane] : 0ull;
            k2 = dpp_max16(k2);            // valid in lane 15
            // ---- ONE relaxed agent store publishes the block winner ----
            if (lane == 15) {
                u32 db  = (u32)(k2 >> 32);
                u32 idx = ~(u32)k2;        // = gi (fits 17 bits)
                __hip_atomic_store(&gsp[chunk],
                                   ((u64)db << 32) | ((u64)idx << 15) | (u64)it,
                                   __ATOMIC_RELAXED, __HIP_MEMORY_SCOPE_AGENT);
            }
            // ---- relaxed poll of the 16 slot words (byte-identical to r8) ----
            u64 v; bool ok;
            do {
                v  = (lane < NBLK)
                       ? __hip_atomic_load(&gsp[lane], __ATOMIC_RELAXED,
                                           __HIP_MEMORY_SCOPE_AGENT)
                       : 0ull;
                ok = (lane < NBLK) ? ((v & 0x7FFFull) == (u64)it) : true;
            } while (__ballot(ok) != ~0ull);
            u64 k3 = 0ull;
            if (lane < NBLK) {
                u32 db  = (u32)(v >> 32);
                u32 idx = (u32)((v >> 15) & 0x1FFFFu);
                k3 = ((u64)db << 32) | (u64)(~idx);
            }
            k3 = dpp_max16(k3);            // valid in lane 15
            if (lane == 15) {
                u32 widx = ~(u32)k3;
                if (chunk == 0) out[b * NSAMP + it] = (int)widx;
                bc = widx;                 // plain store; barrier2 orders it
            }
        }
        __syncthreads();                   // barrier2 (replaces the bc tag-spin)

        u32 widx = bc;                     // barrier-ordered plain read
        cx = bxyz[3 * (size_t)widx + 0];   // same-address broadcast load
        cy = bxyz[3 * (size_t)widx + 1];
        cz = bxyz[3 * (size_t)widx + 2];
    }
}

extern "C" void kernel_launch(void* const* d_in, const int* in_sizes, int n_in,
                              void* d_out, int out_size, void* d_ws, size_t ws_size,
                              hipStream_t stream) {
    const float* xyz = (const float*)d_in[0];
    int* out = (int*)d_out;
    u64* gslot = (u64*)d_ws;   // [BATCH][2][NBLK] u64 = 4 KB

    hipLaunchKernelGGL(fps_init_kernel, dim3(1), dim3(512), 0, stream, gslot);
    hipLaunchKernelGGL(fps_kernel, dim3(BATCH * NBLK), dim3(TPB), 0, stream,
                       xyz, out, gslot);
}